// Round 1
// baseline (844.430 us; speedup 1.0000x reference)
//
#include <hip/hip_runtime.h>

// Problem constants (match reference generator)
#define NCOMP 19      // N_R - 1
#define NB    4096    // batch
#define KSTEPS 1024   // time steps
#define NCH   16      // chunks
#define LCH   64      // steps per chunk (NCH*LCH == KSTEPS)

// workspace layout (float offsets)
#define WS_P    0                                   // 2*19*19 = 722 floats (pad to 1024)
#define WS_DEND 1024                                // NB*NCH*2*NCOMP floats
#define WS_X0   (WS_DEND + NB*NCH*2*NCOMP)          // NB*NCH*2*NCOMP floats

__device__ __forceinline__ void deriv(const float* __restrict__ y, float a, float bin,
                                      float* __restrict__ k) {
#pragma unroll
  for (int j = 0; j < NCOMP; ++j) {
    float s = -2.0f * y[j];
    if (j > 0) s += y[j - 1];
    if (j < NCOMP - 1) s += y[j + 1];
    k[j] = a * s;
  }
  k[NCOMP - 1] += bin;   // input couples only to last component
}

__device__ __forceinline__ void rk4(float* __restrict__ x, float a, float bin) {
  const float h = 0.01f, h2 = 0.005f, h6 = 0.01f / 6.0f;
  float k[NCOMP], y[NCOMP], acc[NCOMP];
  deriv(x, a, bin, k);
#pragma unroll
  for (int j = 0; j < NCOMP; ++j) { acc[j] = k[j]; y[j] = fmaf(h2, k[j], x[j]); }
  deriv(y, a, bin, k);
#pragma unroll
  for (int j = 0; j < NCOMP; ++j) { acc[j] = fmaf(2.0f, k[j], acc[j]); y[j] = fmaf(h2, k[j], x[j]); }
  deriv(y, a, bin, k);
#pragma unroll
  for (int j = 0; j < NCOMP; ++j) { acc[j] = fmaf(2.0f, k[j], acc[j]); y[j] = fmaf(h, k[j], x[j]); }
  deriv(y, a, bin, k);
#pragma unroll
  for (int j = 0; j < NCOMP; ++j) x[j] = fmaf(h6, acc[j] + k[j], x[j]);
}

// Kernel 1: last block computes P = M^LCH columns by propagating basis vectors
//           (zero input); all other blocks compute the driven response per
//           (batch, system, chunk) from a zero start state.
__global__ __launch_bounds__(256) void k1_setup_driven(
    const float* __restrict__ i_seq,
    const float* __restrict__ An, const float* __restrict__ Bn,
    const float* __restrict__ Ap, const float* __restrict__ Bp,
    float* __restrict__ ws)
{
  const float an = An[1];            // alpha_n  (matA[0][1] = alpha)
  const float ap = Ap[1];            // alpha_p
  const float bn = Bn[NCOMP - 1];    // alpha_n * beta_n
  const float bp = Bp[NCOMP - 1];    // alpha_p * beta_p

  if (blockIdx.x == gridDim.x - 1) {
    int t = threadIdx.x;
    if (t < 2 * NCOMP) {
      int sys = t / NCOMP, col = t % NCOMP;
      float a = sys ? ap : an;
      float x[NCOMP];
#pragma unroll
      for (int j = 0; j < NCOMP; ++j) x[j] = 0.0f;
      x[col] = 1.0f;
      for (int s = 0; s < LCH; ++s) rk4(x, a, 0.0f);
#pragma unroll
      for (int j = 0; j < NCOMP; ++j)
        ws[WS_P + (sys * NCOMP + col) * NCOMP + j] = x[j];   // P[j][col] stored col-major
    }
    return;
  }

  int g = blockIdx.x * 256 + threadIdx.x;     // 0 .. NB*2*NCH-1
  int c = g & (NCH - 1);
  int sys = (g >> 4) & 1;
  int b = g >> 5;
  float a = sys ? ap : an;
  float bl = sys ? bp : bn;
  float x[NCOMP];
#pragma unroll
  for (int j = 0; j < NCOMP; ++j) x[j] = 0.0f;
  const float* ip = i_seq + (size_t)b * KSTEPS + c * LCH;
  for (int s = 0; s < LCH; ++s) rk4(x, a, ip[s] * bl);
  float* d = ws + WS_DEND + ((size_t)(b * NCH + c) * 2 + sys) * NCOMP;
#pragma unroll
  for (int j = 0; j < NCOMP; ++j) d[j] = x[j];
}

// Kernel 2: per (batch, system) sequential scan over chunks:
//           X0[b][c] = x;  x = P*x + dend[b][c]
__global__ __launch_bounds__(256) void k2_scan(
    const float* __restrict__ xin, float* __restrict__ ws)
{
  int g = blockIdx.x * 256 + threadIdx.x;   // 0 .. 2*NB-1
  int sys = g >> 12;                         // whole waves share sys
  int b = g & (NB - 1);
  const float* P = ws + WS_P + sys * NCOMP * NCOMP;
  float x[NCOMP];
#pragma unroll
  for (int j = 0; j < NCOMP; ++j) x[j] = xin[(size_t)b * 2 * NCOMP + sys * NCOMP + j];
  for (int c = 0; c < NCH; ++c) {
    size_t idx = ((size_t)(b * NCH + c) * 2 + sys) * NCOMP;
    float* x0 = ws + WS_X0 + idx;
    const float* d = ws + WS_DEND + idx;
    float t[NCOMP];
#pragma unroll
    for (int j = 0; j < NCOMP; ++j) { x0[j] = x[j]; t[j] = d[j]; }
#pragma unroll
    for (int col = 0; col < NCOMP; ++col) {
      float xc = x[col];
#pragma unroll
      for (int j = 0; j < NCOMP; ++j) t[j] = fmaf(xc, P[col * NCOMP + j], t[j]);
    }
#pragma unroll
    for (int j = 0; j < NCOMP; ++j) x[j] = t[j];
  }
}

// Kernel 3: per (batch, system, chunk): resume from X0 and emit all states,
//           buffering 4 timesteps per component for float4 stores.
__global__ __launch_bounds__(256) void k3_emit(
    const float* __restrict__ i_seq,
    const float* __restrict__ An, const float* __restrict__ Bn,
    const float* __restrict__ Ap, const float* __restrict__ Bp,
    const float* __restrict__ ws, float* __restrict__ out)
{
  const float an = An[1];
  const float ap = Ap[1];
  const float bn = Bn[NCOMP - 1];
  const float bp = Bp[NCOMP - 1];

  int g = blockIdx.x * 256 + threadIdx.x;
  int c = g & (NCH - 1);
  int sys = (g >> 4) & 1;
  int b = g >> 5;
  float a = sys ? ap : an;
  float bl = sys ? bp : bn;

  float x[NCOMP];
  const float* x0 = ws + WS_X0 + ((size_t)(b * NCH + c) * 2 + sys) * NCOMP;
#pragma unroll
  for (int j = 0; j < NCOMP; ++j) x[j] = x0[j];

  const float* ip = i_seq + (size_t)b * KSTEPS + c * LCH;
  float* orow = out + ((size_t)b * 2 * NCOMP + sys * NCOMP) * KSTEPS + c * LCH;

  float b0[NCOMP], b1[NCOMP], b2[NCOMP], b3[NCOMP];
  for (int tb = 0; tb < LCH / 4; ++tb) {
#pragma unroll
    for (int u = 0; u < 4; ++u) {
      rk4(x, a, ip[tb * 4 + u] * bl);
      float* dst = (u == 0) ? b0 : (u == 1) ? b1 : (u == 2) ? b2 : b3;
#pragma unroll
      for (int j = 0; j < NCOMP; ++j) dst[j] = x[j];
    }
#pragma unroll
    for (int j = 0; j < NCOMP; ++j) {
      float4 v = make_float4(b0[j], b1[j], b2[j], b3[j]);
      *reinterpret_cast<float4*>(orow + (size_t)j * KSTEPS + tb * 4) = v;
    }
  }
}

extern "C" void kernel_launch(void* const* d_in, const int* in_sizes, int n_in,
                              void* d_out, int out_size, void* d_ws, size_t ws_size,
                              hipStream_t stream) {
  const float* x    = (const float*)d_in[0];
  const float* iseq = (const float*)d_in[1];
  const float* An   = (const float*)d_in[2];
  const float* Bn   = (const float*)d_in[3];
  const float* Ap   = (const float*)d_in[4];
  const float* Bp   = (const float*)d_in[5];
  float* ws  = (float*)d_ws;
  float* out = (float*)d_out;

  const int nthB = NB * 2 * NCH;   // 131072 threads for phases B and D
  k1_setup_driven<<<nthB / 256 + 1, 256, 0, stream>>>(iseq, An, Bn, Ap, Bp, ws);
  k2_scan<<<(NB * 2) / 256, 256, 0, stream>>>(x, ws);
  k3_emit<<<nthB / 256, 256, 0, stream>>>(iseq, An, Bn, Ap, Bp, ws, out);
}